// Round 6
// baseline (824.888 us; speedup 1.0000x reference)
//
#include <hip/hip_runtime.h>

// ---------------------------------------------------------------------------
// TiLISTA: M=512, N=2048, B=8192, T=5 — i8 dual-plane GEMMs, fp32 z/x state.
//   x0 = mu0 * y @ A                      (fp32 in d_out)
//   for t=1..5:
//     r = x @ A^T - y        (fp32 in ws -> per-row i8 planes)
//     z = x - mu_t * (r @ A) (x REPLAYED bit-exactly from z_{t-1}+thr+beta
//                             inside the epilogue; z written in place)
//     x = shrink(z,beta,k)   (planes for next GEMM + thr row; fp32 only t=5)
// GEMM operands: per-row q = q1*128 + q0 (|q|<=16256, ~15 bits of rowmax).
// 3 x mfma_i32_16x16x64_i8 per 64-K: a1b1->accH, a1b0+a0b1->accM;
// v = sA*sB*(accH*16384 + accM*128).
// Grid flat-swizzle: m-block = flat%64 -> same-m blocks share an XCD L2 (R6).
// R9: GEMM schedule rewrite (T2+T3+T4+T5): LDS double-buffer + prefetch-
//   before-compute, raw s_barrier + counted s_waitcnt vmcnt(L), XOR-swizzled
//   tiles (source-side pre-swizzle, read-side XOR), s_setprio around MFMA.
// R10 POST-MORTEM: 2-rows/wave shrink REGRESSED (VGPR 52->112 halved
//   occupancy on a latency-bound kernel). Reverted.
// R11: shrink: ballot counting + uniform early exit (exact same top-k set).
// R12 POST-MORTEM: NJ=2 for big GEMMs REGRESSED (45->55.5 us): A-tile
//   staging per k-step is constant per block -> halving per-block output
//   doubled staging overhead per FLOP. Occupancy was NOT binding. Reverted.
// R13 POST-MORTEM: FAILED (absmax 0.039 > 0.0278). z computed from
//   dequantized x planes added ~3e-5 noise directly on z; top-k tie-flips
//   amplified it (each flip ~ beta ~ 0.0117). RULE: z must come from
//   bit-exact x.
// R14: exact shrink-replay. shrink publishes per-row threshold thr (32 KB)
//   and SKIPS the fp32 x write (t=0..4). The next z-GEMM's epilogue reads
//   z_{t-1} from `out` (the buffer it overwrites) and replays shrink with
//   the IDENTICAL fp32 ops (uint-bit compare, fmaxf, copysignf) -> x is
//   bit-identical to R11, z bit-identical, absmax back to 0.01171875.
//   t=0 stores thr=0 -> replay is identity for t=1. Saves 4 x 64 MB HBM.
// shrink = exact k-th-largest |z| via binary search on float bits.
// ---------------------------------------------------------------------------

typedef int int4v __attribute__((ext_vector_type(4)));

__device__ __forceinline__ void quant2(float v, float inv_s,
                                       signed char& q1, signed char& q0) {
    int q = __float2int_rn(v * inv_s);
    q = q > 16256 ? 16256 : (q < -16256 ? -16256 : q);
    int hi = (q + 64) >> 7;            // round-half-up -> [-127,127]
    q1 = (signed char)hi;
    q0 = (signed char)(q - (hi << 7)); // [-64,63]
}

__device__ __forceinline__ void gl_lds16(const signed char* g, signed char* lds) {
    __builtin_amdgcn_global_load_lds(
        (const __attribute__((address_space(1))) void*)g,
        (__attribute__((address_space(3))) void*)lds, 16, 0, 0);
}

// out[m][n] = epilogue( sum_k Aop[m][k]*Bop[k][n] ); Bop in B^T layout [n][k].
// EPI 0: outF = mu * v                   (x0; A=y planes, B=AT planes)
// EPI 1: outF = v - Yaux                 (r;  A=x planes, B=A planes)
// EPI 2: outF = replay(outF) - mu * v    (z;  A=r planes, B=AT planes;
//         replay(z) = |z|>=thr ? z : copysign(max(|z|-betaPrev,0), z))
template<int NJ, int EPI>
__global__ __launch_bounds__(256, 2) void gemm_i8(
    const signed char* __restrict__ A1, const signed char* __restrict__ A0, int lda,
    const signed char* __restrict__ B1, const signed char* __restrict__ B0, int ldb,
    const float* __restrict__ sAv,   // per-row scale of A-operand
    const float* __restrict__ sBv,   // per-row scale of B-operand (per out col)
    const float* __restrict__ Yaux,  // EPI1: y fp32
    const float* __restrict__ thrv,  // EPI2: per-row shrink threshold (t-1)
    const float* __restrict__ bPrev, // EPI2: &beta[t-1]
    float* __restrict__ outF,
    const float* __restrict__ muPtr, int muIdx, int K, int ldOut)
{
    constexpr int BN = 32 * NJ;      // 128 (NJ=4) or 64 (NJ=2)
    // double-buffered tiles: NJ=4 -> 64 KiB total, NJ=2 -> 48 KiB
    __shared__ signed char As1[2][128 * 64];
    __shared__ signed char As0[2][128 * 64];
    __shared__ signed char Bs1[2][BN * 64];
    __shared__ signed char Bs0[2][BN * 64];

    const int tid  = threadIdx.x;
    const int wid  = tid >> 6;
    const int lane = tid & 63;
    const int quad = lane >> 4;
    const int l16  = lane & 15;
    const int waveM = (wid >> 1) * 64;
    const int waveN = (wid & 1) * (16 * NJ);
    const int swz   = (l16 >> 1) & 3;          // read-side XOR (rows: base%16==0)

    const int flat  = blockIdx.x + gridDim.x * blockIdx.y;
    const int mBase = (flat & 63) * 128;
    const int nBase = (flat >> 6) * BN;

    int4v accH[4][NJ] = {};
    int4v accM[4][NJ] = {};

    // Stage one 64-K tile into buffer b. LDS dest linear (global_load_lds
    // requirement); the global SOURCE chunk is XOR-swizzled so that the
    // ds_read below, applying the same XOR, sees logical chunk order.
    auto stage = [&](int b, int k0) {
        #pragma unroll
        for (int rr = 0; rr < 2; ++rr) {
            int c   = rr * 256 + tid;          // 16B chunk id, 0..511
            int row = c >> 2;
            int js  = (c & 3) ^ ((row >> 1) & 3);
            size_t ga = (size_t)(mBase + row) * lda + k0 + js * 16;
            size_t doff = (size_t)((rr * 256 + wid * 64) * 16);
            gl_lds16(A1 + ga, As1[b] + doff);
            gl_lds16(A0 + ga, As0[b] + doff);
        }
        // chunk count = BN*64B / 16B = BN*4; iterations = BN*4/256 = BN/64
        #pragma unroll
        for (int rr = 0; rr < BN / 64; ++rr) {
            int c   = rr * 256 + tid;
            int row = c >> 2;
            int js  = (c & 3) ^ ((row >> 1) & 3);
            size_t gb = (size_t)(nBase + row) * ldb + k0 + js * 16;
            size_t doff = (size_t)((rr * 256 + wid * 64) * 16);
            gl_lds16(B1 + gb, Bs1[b] + doff);
            gl_lds16(B0 + gb, Bs0[b] + doff);
        }
    };

    const int KT = K >> 6;
    stage(0, 0);

    for (int kt = 0; kt < KT; ++kt) {
        const int cur = kt & 1;
        if (kt + 1 < KT) {
            stage(cur ^ 1, (kt + 1) << 6);
            // wait tile-kt's loads only; tile-(kt+1)'s L loads stay in flight
            if constexpr (NJ == 4) asm volatile("s_waitcnt vmcnt(8)" ::: "memory");
            else                   asm volatile("s_waitcnt vmcnt(6)" ::: "memory");
        } else {
            asm volatile("s_waitcnt vmcnt(0)" ::: "memory");
        }
        __builtin_amdgcn_s_barrier();          // raw: no vmcnt drain

        int4v a1[4], a0[4], b1[NJ], b0[NJ];
        #pragma unroll
        for (int i = 0; i < 4; ++i) {
            int off = (waveM + i * 16 + l16) * 64 + ((quad ^ swz) * 16);
            a1[i] = *(const int4v*)(&As1[cur][off]);
            a0[i] = *(const int4v*)(&As0[cur][off]);
        }
        #pragma unroll
        for (int j = 0; j < NJ; ++j) {
            int off = (waveN + j * 16 + l16) * 64 + ((quad ^ swz) * 16);
            b1[j] = *(const int4v*)(&Bs1[cur][off]);
            b0[j] = *(const int4v*)(&Bs0[cur][off]);
        }
        __builtin_amdgcn_s_setprio(1);
        #pragma unroll
        for (int i = 0; i < 4; ++i)
            #pragma unroll
            for (int j = 0; j < NJ; ++j) {
                accH[i][j] = __builtin_amdgcn_mfma_i32_16x16x64_i8(a1[i], b1[j], accH[i][j], 0, 0, 0);
                accM[i][j] = __builtin_amdgcn_mfma_i32_16x16x64_i8(a1[i], b0[j], accM[i][j], 0, 0, 0);
                accM[i][j] = __builtin_amdgcn_mfma_i32_16x16x64_i8(a0[i], b1[j], accM[i][j], 0, 0, 0);
            }
        __builtin_amdgcn_s_setprio(0);
        __builtin_amdgcn_s_barrier();          // reads of buf[cur] done before
                                               // next iter's stage overwrites it
    }

    const float mu = muPtr[muIdx];
    const float betaPrev = (EPI == 2) ? bPrev[0] : 0.f;
    #pragma unroll
    for (int i = 0; i < 4; ++i) {
        #pragma unroll
        for (int j = 0; j < NJ; ++j) {
            const int gr0 = mBase + waveM + i * 16 + quad * 4;
            const int gc  = nBase + waveN + j * 16 + l16;
            const float sB = sBv[gc];
            #pragma unroll
            for (int r2 = 0; r2 < 4; ++r2) {
                const int    gr  = gr0 + r2;
                const size_t idx = (size_t)gr * ldOut + gc;
                const float  sA  = sAv[gr];
                float v = sA * sB * ((float)accH[i][j][r2] * 16384.f
                                   + (float)accM[i][j][r2] * 128.f);
                if constexpr (EPI == 0) {
                    outF[idx] = mu * v;
                } else if constexpr (EPI == 1) {
                    outF[idx] = v - Yaux[idx];
                } else {
                    // bit-exact shrink replay of z_{t-1} (same ops as
                    // shrink_kernel: uint-bit compare, fmaxf, copysignf)
                    const float    zp = outF[idx];
                    const unsigned ab = __float_as_uint(fabsf(zp));
                    float xv;
                    if (ab >= __float_as_uint(thrv[gr])) {
                        xv = zp;
                    } else {
                        xv = copysignf(
                            fmaxf(__uint_as_float(ab) - betaPrev, 0.f), zp);
                    }
                    outF[idx] = xv - mu * v;
                }
            }
        }
    }
}

// per-row quantization of a fp32 matrix to i8 dual planes + row scale
template<int COLS>
__global__ __launch_bounds__(256) void rowquant_kernel(
    const float* __restrict__ src,
    signed char* __restrict__ q1, signed char* __restrict__ q0,
    float* __restrict__ scale)
{
    const int wid  = threadIdx.x >> 6;
    const int lane = threadIdx.x & 63;
    const long long row = (long long)blockIdx.x * 4 + wid;
    constexpr int EP = COLS / 256;   // float4 per lane
    const float* s = src + row * COLS;

    float v[EP * 4];
    #pragma unroll
    for (int c = 0; c < EP; ++c) {
        float4 f = ((const float4*)s)[c * 64 + lane];
        v[c * 4 + 0] = f.x; v[c * 4 + 1] = f.y; v[c * 4 + 2] = f.z; v[c * 4 + 3] = f.w;
    }
    float mx = 0.f;
    #pragma unroll
    for (int i = 0; i < EP * 4; ++i) mx = fmaxf(mx, fabsf(v[i]));
    #pragma unroll
    for (int off = 32; off >= 1; off >>= 1) mx = fmaxf(mx, __shfl_xor(mx, off, 64));
    mx = fmaxf(mx, 1e-20f);
    if (lane == 0) scale[row] = mx / 16256.f;
    const float inv = 16256.f / mx;

    #pragma unroll
    for (int c = 0; c < EP; ++c) {
        size_t col = (size_t)(c * 64 + lane) * 4;
        signed char h[4], l[4];
        #pragma unroll
        for (int e = 0; e < 4; ++e) quant2(v[c * 4 + e], inv, h[e], l[e]);
        *(char4*)(q1 + row * COLS + col) = *(char4*)h;
        *(char4*)(q0 + row * COLS + col) = *(char4*)l;
    }
}

// R11/R14: one wave per row of z[.,2048]: exact k-th-largest |z| hard/soft
// threshold via scalar binary search on float bits with ballot counting +
// uniform early exit. Publishes per-row thr (for the next z-GEMM's exact
// replay), quantizes x -> i8 planes + scale (writePlanes), optionally
// writes x fp32 (writeF32, final iteration only).
__global__ __launch_bounds__(256) void shrink_kernel(
    float* __restrict__ z,
    signed char* __restrict__ X1, signed char* __restrict__ X0,
    float* __restrict__ sX, float* __restrict__ thrOut,
    const float* __restrict__ betaPtr, int tIdx, int kSel,
    int writeF32, int writePlanes)
{
    const int wid  = threadIdx.x >> 6;
    const int lane = threadIdx.x & 63;
    const long long row = (long long)blockIdx.x * 4 + wid;
    float* zr = z + row * 2048;

    float v[32];
    #pragma unroll
    for (int c = 0; c < 8; ++c) {
        float4 f = ((const float4*)zr)[c * 64 + lane];
        v[c * 4 + 0] = f.x; v[c * 4 + 1] = f.y; v[c * 4 + 2] = f.z; v[c * 4 + 3] = f.w;
    }

    if (kSel > 0) {
        const float beta = betaPtr[tIdx];
        unsigned a[32];
        #pragma unroll
        for (int i = 0; i < 32; ++i) a[i] = __float_as_uint(fabsf(v[i]));

        // invariant: cnt(>=lo) >= k, cnt(>=hi) < k. Early exit: any mid
        // with cnt(>=mid)==k classifies exactly the top-k set (identical
        // to thr = k-th largest); a tie straddling k makes cnt==k
        // unreachable -> loop runs to convergence (thr = v_k), also exact.
        unsigned lo = 0u, hi = 0x7F800000u;
        #pragma unroll 1
        for (int it = 0; it < 31; ++it) {
            const unsigned mid = (lo + hi) >> 1;
            int cnt = 0;
            #pragma unroll
            for (int i = 0; i < 32; ++i)
                cnt += (int)__popcll(__ballot(a[i] >= mid));
            if (cnt >= kSel) {
                lo = mid;
                if (cnt == kSel) break;
            } else {
                hi = mid;
            }
        }
        const unsigned thr = lo;
        if (lane == 0) thrOut[row] = __uint_as_float(thr);
        #pragma unroll
        for (int i = 0; i < 32; ++i) {
            if (a[i] < thr) {
                float av   = __uint_as_float(a[i]);
                float soft = fmaxf(av - beta, 0.f);
                v[i] = copysignf(soft, v[i]);
            }
        }
    } else {
        // no thresholding this step: replay must be identity -> thr = 0
        if (lane == 0) thrOut[row] = 0.f;
    }

    float mx = 0.f;
    #pragma unroll
    for (int i = 0; i < 32; ++i) mx = fmaxf(mx, fabsf(v[i]));
    #pragma unroll
    for (int off = 32; off >= 1; off >>= 1) mx = fmaxf(mx, __shfl_xor(mx, off, 64));
    mx = fmaxf(mx, 1e-20f);
    if (writePlanes && lane == 0) sX[row] = mx / 16256.f;
    const float inv = 16256.f / mx;

    #pragma unroll
    for (int c = 0; c < 8; ++c) {
        size_t col = (size_t)(c * 64 + lane) * 4;
        if (writePlanes) {
            signed char h[4], l[4];
            #pragma unroll
            for (int e = 0; e < 4; ++e) quant2(v[c * 4 + e], inv, h[e], l[e]);
            *(char4*)(X1 + row * 2048 + col) = *(char4*)h;
            *(char4*)(X0 + row * 2048 + col) = *(char4*)l;
        }
        if (writeF32) {
            float4 f;
            f.x = v[c * 4 + 0]; f.y = v[c * 4 + 1]; f.z = v[c * 4 + 2]; f.w = v[c * 4 + 3];
            ((float4*)zr)[c * 64 + lane] = f;
        }
    }
}

extern "C" void kernel_launch(void* const* d_in, const int* in_sizes, int n_in,
                              void* d_out, int out_size, void* d_ws, size_t ws_size,
                              hipStream_t stream)
{
    const float* y    = (const float*)d_in[0];   // [8192,512]
    const float* A    = (const float*)d_in[1];   // [512,2048]
    const float* W    = (const float*)d_in[2];   // [2048,512] == A^T
    const float* beta = (const float*)d_in[3];   // [6]
    const float* mu   = (const float*)d_in[4];   // [6]
    float* out = (float*)d_out;                  // x / z fp32, in place

    // workspace (~68 MB)
    signed char* A1q  = (signed char*)d_ws;          // [512][2048]
    signed char* A0q  = A1q  + 512 * 2048;
    signed char* AT1q = A0q  + 512 * 2048;           // [2048][512]
    signed char* AT0q = AT1q + 2048 * 512;
    signed char* y1q  = AT0q + 2048 * 512;           // [8192][512]
    signed char* y0q  = y1q  + 8192 * 512;
    signed char* x1q  = y0q  + 8192 * 512;           // [8192][2048]
    signed char* x0q  = x1q  + (size_t)8192 * 2048;
    signed char* r1q  = x0q  + (size_t)8192 * 2048;  // [8192][512]
    signed char* r0q  = r1q  + 8192 * 512;
    float* rF  = (float*)(r0q + 8192 * 512);         // [8192][512] fp32
    float* sa  = rF + (size_t)8192 * 512;            // [512]
    float* sat = sa  + 512;                          // [2048]
    float* sy  = sat + 2048;                         // [8192]
    float* sx  = sy  + 8192;                         // [8192]
    float* sr  = sx  + 8192;                         // [8192]
    float* thr = sr  + 8192;                         // [8192]

    rowquant_kernel<2048><<<128, 256, 0, stream>>>(A, A1q, A0q, sa);
    rowquant_kernel<512><<<512, 256, 0, stream>>>(W, AT1q, AT0q, sat);
    rowquant_kernel<512><<<2048, 256, 0, stream>>>(y, y1q, y0q, sy);

    // x0 = mu0 * y @ A  -> d_out fp32   (A-op = y planes, B-op = AT planes)
    gemm_i8<4, 0><<<dim3(16, 64), 256, 0, stream>>>(
        y1q, y0q, 512, AT1q, AT0q, 512, sy, sat,
        nullptr, nullptr, nullptr, out, mu, 0, 512, 2048);
    // quantize x0 for GEMM use; thr=0 so the t=1 replay is identity
    shrink_kernel<<<2048, 256, 0, stream>>>(out, x1q, x0q, sx, thr, beta,
                                            0, 0, 0, 1);

    for (int t = 1; t <= 5; ++t) {
        double p = 0.012 * t; if (p > 0.12) p = 0.12;
        int kSel = (int)(p * 2048.0);   // 24,49,73,98,122

        // r = x @ A^T - y  -> rF fp32   (A-op = x planes, B-op = A planes)
        gemm_i8<2, 1><<<dim3(8, 64), 256, 0, stream>>>(
            x1q, x0q, 2048, A1q, A0q, 2048, sx, sa,
            y, nullptr, nullptr, rF, mu, t, 2048, 512);
        // quantize r per-row
        rowquant_kernel<512><<<2048, 256, 0, stream>>>(rF, r1q, r0q, sr);

        // z = replay(z_{t-1}) - mu_t * (r @ A)  in place over d_out
        gemm_i8<4, 2><<<dim3(16, 64), 256, 0, stream>>>(
            r1q, r0q, 512, AT1q, AT0q, 512, sr, sat,
            nullptr, thr, beta + (t - 1), out, mu, t, 512, 2048);

        // x = shrink(z): t<5 -> planes+thr only; t=5 -> fp32 output only
        shrink_kernel<<<2048, 256, 0, stream>>>(out, x1q, x0q, sx, thr, beta,
                                                t, kSel, t == 5 ? 1 : 0,
                                                t < 5 ? 1 : 0);
    }
}

// Round 7
// 736.809 us; speedup vs baseline: 1.1195x; 1.1195x over previous
//
#include <hip/hip_runtime.h>

// ---------------------------------------------------------------------------
// TiLISTA: M=512, N=2048, B=8192, T=5 — i8 dual-plane GEMMs, fp32 z/x state.
//   x0 = mu0 * y @ A                      (fp32 in d_out)
//   for t=1..5:
//     r = x @ A^T - y        (fp32 in ws -> per-row i8 planes)
//     z = x - mu_t * (r @ A) (x REPLAYED bit-exactly from z_{t-1}+thr+beta
//                             inside the epilogue; z written in place)
//     x = shrink(z,beta,k)   (planes for next GEMM + thr row; fp32 only t=5)
// GEMM operands: per-row q = q1*128 + q0 (|q|<=16256, ~15 bits of rowmax).
// 3 x mfma_i32_16x16x64_i8 per 64-K: a1b1->accH, a1b0+a0b1->accM;
// v = sA*sB*(accH*16384 + accM*128).
// Grid flat-swizzle: m-block = flat%64 -> same-m blocks share an XCD L2 (R6).
// R9: GEMM schedule rewrite (T2+T3+T4+T5): LDS double-buffer + prefetch-
//   before-compute, raw s_barrier + counted s_waitcnt vmcnt(L), XOR-swizzled
//   tiles (source-side pre-swizzle, read-side XOR), s_setprio around MFMA.
// R10 POST-MORTEM: 2-rows/wave shrink REGRESSED (VGPR 52->112 halved
//   occupancy on a latency-bound kernel). Reverted.
// R11: shrink: ballot counting + uniform early exit (exact same top-k set).
// R12 POST-MORTEM: NJ=2 for big GEMMs REGRESSED (45->55.5 us): A-tile
//   staging per k-step is constant per block -> halving per-block output
//   doubled staging overhead per FLOP. Occupancy was NOT binding. Reverted.
// R13 POST-MORTEM: FAILED (absmax 0.039). z from dequantized x planes added
//   ~3e-5 noise on z; top-k tie-flips amplified it. RULE: z needs exact x.
// R14 POST-MORTEM: shrink-replay passed bit-exact BUT z-GEMM 45->66 us at
//   IDENTICAL traffic: epilogue read outF[idx] through the same non-const
//   pointer it writes -> compiler assumed aliasing -> 64 serialized
//   load->compute->store chains. Ordering effect, not bandwidth.
// R15: same algorithm, R11's aliasing structure: z_{t-1} is read via a
//   separate `const float* __restrict__ Zprev` (points at out, exactly like
//   R11's Yaux which measured 45 us). Per-idx safety: one lane owns each
//   idx; the store value depends on the load -> dataflow orders same-idx;
//   cross-idx reorder is harmless (disjoint).
// shrink = exact k-th-largest |z| via binary search on float bits.
// ---------------------------------------------------------------------------

typedef int int4v __attribute__((ext_vector_type(4)));

__device__ __forceinline__ void quant2(float v, float inv_s,
                                       signed char& q1, signed char& q0) {
    int q = __float2int_rn(v * inv_s);
    q = q > 16256 ? 16256 : (q < -16256 ? -16256 : q);
    int hi = (q + 64) >> 7;            // round-half-up -> [-127,127]
    q1 = (signed char)hi;
    q0 = (signed char)(q - (hi << 7)); // [-64,63]
}

__device__ __forceinline__ void gl_lds16(const signed char* g, signed char* lds) {
    __builtin_amdgcn_global_load_lds(
        (const __attribute__((address_space(1))) void*)g,
        (__attribute__((address_space(3))) void*)lds, 16, 0, 0);
}

// out[m][n] = epilogue( sum_k Aop[m][k]*Bop[k][n] ); Bop in B^T layout [n][k].
// EPI 0: outF = mu * v                   (x0; A=y planes, B=AT planes)
// EPI 1: outF = v - Yaux                 (r;  A=x planes, B=A planes)
// EPI 2: outF = replay(Zprev) - mu * v   (z;  A=r planes, B=AT planes;
//         replay(z) = |z|>=thr ? z : copysign(max(|z|-betaPrev,0), z))
template<int NJ, int EPI>
__global__ __launch_bounds__(256, 2) void gemm_i8(
    const signed char* __restrict__ A1, const signed char* __restrict__ A0, int lda,
    const signed char* __restrict__ B1, const signed char* __restrict__ B0, int ldb,
    const float* __restrict__ sAv,   // per-row scale of A-operand
    const float* __restrict__ sBv,   // per-row scale of B-operand (per out col)
    const float* __restrict__ Yaux,  // EPI1: y fp32
    const float* __restrict__ Zprev, // EPI2: z_{t-1} fp32 (= outF buffer)
    const float* __restrict__ thrv,  // EPI2: per-row shrink threshold (t-1)
    const float* __restrict__ bPrev, // EPI2: &beta[t-1]
    float* __restrict__ outF,
    const float* __restrict__ muPtr, int muIdx, int K, int ldOut)
{
    constexpr int BN = 32 * NJ;      // 128 (NJ=4) or 64 (NJ=2)
    // double-buffered tiles: NJ=4 -> 64 KiB total, NJ=2 -> 48 KiB
    __shared__ signed char As1[2][128 * 64];
    __shared__ signed char As0[2][128 * 64];
    __shared__ signed char Bs1[2][BN * 64];
    __shared__ signed char Bs0[2][BN * 64];

    const int tid  = threadIdx.x;
    const int wid  = tid >> 6;
    const int lane = tid & 63;
    const int quad = lane >> 4;
    const int l16  = lane & 15;
    const int waveM = (wid >> 1) * 64;
    const int waveN = (wid & 1) * (16 * NJ);
    const int swz   = (l16 >> 1) & 3;          // read-side XOR (rows: base%16==0)

    const int flat  = blockIdx.x + gridDim.x * blockIdx.y;
    const int mBase = (flat & 63) * 128;
    const int nBase = (flat >> 6) * BN;

    int4v accH[4][NJ] = {};
    int4v accM[4][NJ] = {};

    // Stage one 64-K tile into buffer b. LDS dest linear (global_load_lds
    // requirement); the global SOURCE chunk is XOR-swizzled so that the
    // ds_read below, applying the same XOR, sees logical chunk order.
    auto stage = [&](int b, int k0) {
        #pragma unroll
        for (int rr = 0; rr < 2; ++rr) {
            int c   = rr * 256 + tid;          // 16B chunk id, 0..511
            int row = c >> 2;
            int js  = (c & 3) ^ ((row >> 1) & 3);
            size_t ga = (size_t)(mBase + row) * lda + k0 + js * 16;
            size_t doff = (size_t)((rr * 256 + wid * 64) * 16);
            gl_lds16(A1 + ga, As1[b] + doff);
            gl_lds16(A0 + ga, As0[b] + doff);
        }
        // chunk count = BN*64B / 16B = BN*4; iterations = BN*4/256 = BN/64
        #pragma unroll
        for (int rr = 0; rr < BN / 64; ++rr) {
            int c   = rr * 256 + tid;
            int row = c >> 2;
            int js  = (c & 3) ^ ((row >> 1) & 3);
            size_t gb = (size_t)(nBase + row) * ldb + k0 + js * 16;
            size_t doff = (size_t)((rr * 256 + wid * 64) * 16);
            gl_lds16(B1 + gb, Bs1[b] + doff);
            gl_lds16(B0 + gb, Bs0[b] + doff);
        }
    };

    const int KT = K >> 6;
    stage(0, 0);

    for (int kt = 0; kt < KT; ++kt) {
        const int cur = kt & 1;
        if (kt + 1 < KT) {
            stage(cur ^ 1, (kt + 1) << 6);
            // wait tile-kt's loads only; tile-(kt+1)'s L loads stay in flight
            if constexpr (NJ == 4) asm volatile("s_waitcnt vmcnt(8)" ::: "memory");
            else                   asm volatile("s_waitcnt vmcnt(6)" ::: "memory");
        } else {
            asm volatile("s_waitcnt vmcnt(0)" ::: "memory");
        }
        __builtin_amdgcn_s_barrier();          // raw: no vmcnt drain

        int4v a1[4], a0[4], b1[NJ], b0[NJ];
        #pragma unroll
        for (int i = 0; i < 4; ++i) {
            int off = (waveM + i * 16 + l16) * 64 + ((quad ^ swz) * 16);
            a1[i] = *(const int4v*)(&As1[cur][off]);
            a0[i] = *(const int4v*)(&As0[cur][off]);
        }
        #pragma unroll
        for (int j = 0; j < NJ; ++j) {
            int off = (waveN + j * 16 + l16) * 64 + ((quad ^ swz) * 16);
            b1[j] = *(const int4v*)(&Bs1[cur][off]);
            b0[j] = *(const int4v*)(&Bs0[cur][off]);
        }
        __builtin_amdgcn_s_setprio(1);
        #pragma unroll
        for (int i = 0; i < 4; ++i)
            #pragma unroll
            for (int j = 0; j < NJ; ++j) {
                accH[i][j] = __builtin_amdgcn_mfma_i32_16x16x64_i8(a1[i], b1[j], accH[i][j], 0, 0, 0);
                accM[i][j] = __builtin_amdgcn_mfma_i32_16x16x64_i8(a1[i], b0[j], accM[i][j], 0, 0, 0);
                accM[i][j] = __builtin_amdgcn_mfma_i32_16x16x64_i8(a0[i], b1[j], accM[i][j], 0, 0, 0);
            }
        __builtin_amdgcn_s_setprio(0);
        __builtin_amdgcn_s_barrier();          // reads of buf[cur] done before
                                               // next iter's stage overwrites it
    }

    const float mu = muPtr[muIdx];
    const float betaPrev = (EPI == 2) ? bPrev[0] : 0.f;
    #pragma unroll
    for (int i = 0; i < 4; ++i) {
        #pragma unroll
        for (int j = 0; j < NJ; ++j) {
            const int gr0 = mBase + waveM + i * 16 + quad * 4;
            const int gc  = nBase + waveN + j * 16 + l16;
            const float sB = sBv[gc];
            #pragma unroll
            for (int r2 = 0; r2 < 4; ++r2) {
                const int    gr  = gr0 + r2;
                const size_t idx = (size_t)gr * ldOut + gc;
                const float  sA  = sAv[gr];
                float v = sA * sB * ((float)accH[i][j][r2] * 16384.f
                                   + (float)accM[i][j][r2] * 128.f);
                if constexpr (EPI == 0) {
                    outF[idx] = mu * v;
                } else if constexpr (EPI == 1) {
                    outF[idx] = v - Yaux[idx];
                } else {
                    // bit-exact shrink replay of z_{t-1} (same ops as
                    // shrink_kernel: uint-bit compare, fmaxf, copysignf)
                    const float    zp = Zprev[idx];
                    const unsigned ab = __float_as_uint(fabsf(zp));
                    float xv;
                    if (ab >= __float_as_uint(thrv[gr])) {
                        xv = zp;
                    } else {
                        xv = copysignf(
                            fmaxf(__uint_as_float(ab) - betaPrev, 0.f), zp);
                    }
                    outF[idx] = xv - mu * v;
                }
            }
        }
    }
}

// per-row quantization of a fp32 matrix to i8 dual planes + row scale
template<int COLS>
__global__ __launch_bounds__(256) void rowquant_kernel(
    const float* __restrict__ src,
    signed char* __restrict__ q1, signed char* __restrict__ q0,
    float* __restrict__ scale)
{
    const int wid  = threadIdx.x >> 6;
    const int lane = threadIdx.x & 63;
    const long long row = (long long)blockIdx.x * 4 + wid;
    constexpr int EP = COLS / 256;   // float4 per lane
    const float* s = src + row * COLS;

    float v[EP * 4];
    #pragma unroll
    for (int c = 0; c < EP; ++c) {
        float4 f = ((const float4*)s)[c * 64 + lane];
        v[c * 4 + 0] = f.x; v[c * 4 + 1] = f.y; v[c * 4 + 2] = f.z; v[c * 4 + 3] = f.w;
    }
    float mx = 0.f;
    #pragma unroll
    for (int i = 0; i < EP * 4; ++i) mx = fmaxf(mx, fabsf(v[i]));
    #pragma unroll
    for (int off = 32; off >= 1; off >>= 1) mx = fmaxf(mx, __shfl_xor(mx, off, 64));
    mx = fmaxf(mx, 1e-20f);
    if (lane == 0) scale[row] = mx / 16256.f;
    const float inv = 16256.f / mx;

    #pragma unroll
    for (int c = 0; c < EP; ++c) {
        size_t col = (size_t)(c * 64 + lane) * 4;
        signed char h[4], l[4];
        #pragma unroll
        for (int e = 0; e < 4; ++e) quant2(v[c * 4 + e], inv, h[e], l[e]);
        *(char4*)(q1 + row * COLS + col) = *(char4*)h;
        *(char4*)(q0 + row * COLS + col) = *(char4*)l;
    }
}

// R11/R14: one wave per row of z[.,2048]: exact k-th-largest |z| hard/soft
// threshold via scalar binary search on float bits with ballot counting +
// uniform early exit. Publishes per-row thr (for the next z-GEMM's exact
// replay), quantizes x -> i8 planes + scale (writePlanes), optionally
// writes x fp32 (writeF32, final iteration only).
__global__ __launch_bounds__(256) void shrink_kernel(
    float* __restrict__ z,
    signed char* __restrict__ X1, signed char* __restrict__ X0,
    float* __restrict__ sX, float* __restrict__ thrOut,
    const float* __restrict__ betaPtr, int tIdx, int kSel,
    int writeF32, int writePlanes)
{
    const int wid  = threadIdx.x >> 6;
    const int lane = threadIdx.x & 63;
    const long long row = (long long)blockIdx.x * 4 + wid;
    float* zr = z + row * 2048;

    float v[32];
    #pragma unroll
    for (int c = 0; c < 8; ++c) {
        float4 f = ((const float4*)zr)[c * 64 + lane];
        v[c * 4 + 0] = f.x; v[c * 4 + 1] = f.y; v[c * 4 + 2] = f.z; v[c * 4 + 3] = f.w;
    }

    if (kSel > 0) {
        const float beta = betaPtr[tIdx];
        unsigned a[32];
        #pragma unroll
        for (int i = 0; i < 32; ++i) a[i] = __float_as_uint(fabsf(v[i]));

        // invariant: cnt(>=lo) >= k, cnt(>=hi) < k. Early exit: any mid
        // with cnt(>=mid)==k classifies exactly the top-k set (identical
        // to thr = k-th largest); a tie straddling k makes cnt==k
        // unreachable -> loop runs to convergence (thr = v_k), also exact.
        unsigned lo = 0u, hi = 0x7F800000u;
        #pragma unroll 1
        for (int it = 0; it < 31; ++it) {
            const unsigned mid = (lo + hi) >> 1;
            int cnt = 0;
            #pragma unroll
            for (int i = 0; i < 32; ++i)
                cnt += (int)__popcll(__ballot(a[i] >= mid));
            if (cnt >= kSel) {
                lo = mid;
                if (cnt == kSel) break;
            } else {
                hi = mid;
            }
        }
        const unsigned thr = lo;
        if (lane == 0) thrOut[row] = __uint_as_float(thr);
        #pragma unroll
        for (int i = 0; i < 32; ++i) {
            if (a[i] < thr) {
                float av   = __uint_as_float(a[i]);
                float soft = fmaxf(av - beta, 0.f);
                v[i] = copysignf(soft, v[i]);
            }
        }
    } else {
        // no thresholding this step: replay must be identity -> thr = 0
        if (lane == 0) thrOut[row] = 0.f;
    }

    float mx = 0.f;
    #pragma unroll
    for (int i = 0; i < 32; ++i) mx = fmaxf(mx, fabsf(v[i]));
    #pragma unroll
    for (int off = 32; off >= 1; off >>= 1) mx = fmaxf(mx, __shfl_xor(mx, off, 64));
    mx = fmaxf(mx, 1e-20f);
    if (writePlanes && lane == 0) sX[row] = mx / 16256.f;
    const float inv = 16256.f / mx;

    #pragma unroll
    for (int c = 0; c < 8; ++c) {
        size_t col = (size_t)(c * 64 + lane) * 4;
        if (writePlanes) {
            signed char h[4], l[4];
            #pragma unroll
            for (int e = 0; e < 4; ++e) quant2(v[c * 4 + e], inv, h[e], l[e]);
            *(char4*)(X1 + row * 2048 + col) = *(char4*)h;
            *(char4*)(X0 + row * 2048 + col) = *(char4*)l;
        }
        if (writeF32) {
            float4 f;
            f.x = v[c * 4 + 0]; f.y = v[c * 4 + 1]; f.z = v[c * 4 + 2]; f.w = v[c * 4 + 3];
            ((float4*)zr)[c * 64 + lane] = f;
        }
    }
}

extern "C" void kernel_launch(void* const* d_in, const int* in_sizes, int n_in,
                              void* d_out, int out_size, void* d_ws, size_t ws_size,
                              hipStream_t stream)
{
    const float* y    = (const float*)d_in[0];   // [8192,512]
    const float* A    = (const float*)d_in[1];   // [512,2048]
    const float* W    = (const float*)d_in[2];   // [2048,512] == A^T
    const float* beta = (const float*)d_in[3];   // [6]
    const float* mu   = (const float*)d_in[4];   // [6]
    float* out = (float*)d_out;                  // x / z fp32, in place

    // workspace (~68 MB)
    signed char* A1q  = (signed char*)d_ws;          // [512][2048]
    signed char* A0q  = A1q  + 512 * 2048;
    signed char* AT1q = A0q  + 512 * 2048;           // [2048][512]
    signed char* AT0q = AT1q + 2048 * 512;
    signed char* y1q  = AT0q + 2048 * 512;           // [8192][512]
    signed char* y0q  = y1q  + 8192 * 512;
    signed char* x1q  = y0q  + 8192 * 512;           // [8192][2048]
    signed char* x0q  = x1q  + (size_t)8192 * 2048;
    signed char* r1q  = x0q  + (size_t)8192 * 2048;  // [8192][512]
    signed char* r0q  = r1q  + 8192 * 512;
    float* rF  = (float*)(r0q + 8192 * 512);         // [8192][512] fp32
    float* sa  = rF + (size_t)8192 * 512;            // [512]
    float* sat = sa  + 512;                          // [2048]
    float* sy  = sat + 2048;                         // [8192]
    float* sx  = sy  + 8192;                         // [8192]
    float* sr  = sx  + 8192;                         // [8192]
    float* thr = sr  + 8192;                         // [8192]

    rowquant_kernel<2048><<<128, 256, 0, stream>>>(A, A1q, A0q, sa);
    rowquant_kernel<512><<<512, 256, 0, stream>>>(W, AT1q, AT0q, sat);
    rowquant_kernel<512><<<2048, 256, 0, stream>>>(y, y1q, y0q, sy);

    // x0 = mu0 * y @ A  -> d_out fp32   (A-op = y planes, B-op = AT planes)
    gemm_i8<4, 0><<<dim3(16, 64), 256, 0, stream>>>(
        y1q, y0q, 512, AT1q, AT0q, 512, sy, sat,
        nullptr, nullptr, nullptr, nullptr, out, mu, 0, 512, 2048);
    // quantize x0 for GEMM use; thr=0 so the t=1 replay is identity
    shrink_kernel<<<2048, 256, 0, stream>>>(out, x1q, x0q, sx, thr, beta,
                                            0, 0, 0, 1);

    for (int t = 1; t <= 5; ++t) {
        double p = 0.012 * t; if (p > 0.12) p = 0.12;
        int kSel = (int)(p * 2048.0);   // 24,49,73,98,122

        // r = x @ A^T - y  -> rF fp32   (A-op = x planes, B-op = A planes)
        gemm_i8<2, 1><<<dim3(8, 64), 256, 0, stream>>>(
            x1q, x0q, 2048, A1q, A0q, 2048, sx, sa,
            y, nullptr, nullptr, nullptr, rF, mu, t, 2048, 512);
        // quantize r per-row
        rowquant_kernel<512><<<2048, 256, 0, stream>>>(rF, r1q, r0q, sr);

        // z = replay(z_{t-1}) - mu_t * (r @ A)  in place over d_out
        // (Zprev = out read via const __restrict__, R11's measured-fast form)
        gemm_i8<4, 2><<<dim3(16, 64), 256, 0, stream>>>(
            r1q, r0q, 512, AT1q, AT0q, 512, sr, sat,
            nullptr, out, thr, beta + (t - 1), out, mu, t, 512, 2048);

        // x = shrink(z): t<5 -> planes+thr only; t=5 -> fp32 output only
        shrink_kernel<<<2048, 256, 0, stream>>>(out, x1q, x0q, sx, thr, beta,
                                                t, kSel, t == 5 ? 1 : 0,
                                                t < 5 ? 1 : 0);
    }
}

// Round 8
// 732.243 us; speedup vs baseline: 1.1265x; 1.0062x over previous
//
#include <hip/hip_runtime.h>

// ---------------------------------------------------------------------------
// TiLISTA: M=512, N=2048, B=8192, T=5 — i8 dual-plane GEMMs, fp32 z/x state.
//   x0 = mu0 * y @ A                      (fp32 in d_out)
//   for t=1..5:
//     r = x @ A^T - y        (fp32 in ws -> per-row i8 planes)
//     z = x - mu_t * (r @ A) (x REPLAYED bit-exactly from z_{t-1}+thr+beta
//                             inside the epilogue; z written in place)
//     x = shrink(z,beta,k)   (planes for next GEMM + thr row; fp32 only t=5)
// GEMM operands: per-row q = q1*128 + q0 (|q|<=16256, ~15 bits of rowmax).
// 3 x mfma_i32_16x16x64_i8 per 64-K: a1b1->accH, a1b0+a0b1->accM;
// v = sA*sB*(accH*16384 + accM*128).
// Grid flat-swizzle: m-block = flat%64 -> same-m blocks share an XCD L2 (R6).
// R9: GEMM schedule rewrite (T2+T3+T4+T5): LDS double-buffer + prefetch-
//   before-compute, raw s_barrier + counted s_waitcnt vmcnt(L), XOR-swizzled
//   tiles (source-side pre-swizzle, read-side XOR), s_setprio around MFMA.
// R10 POST-MORTEM: 2-rows/wave shrink REGRESSED (VGPR doubled, occupancy
//   halved on a latency-bound kernel). Reverted.
// R11: shrink: ballot counting + uniform early exit (exact same top-k set).
// R12 POST-MORTEM: NJ=2 for big GEMMs REGRESSED: A-tile staging per k-step
//   is constant per block -> halving per-block output doubled staging
//   overhead per FLOP. Reverted.
// R13 POST-MORTEM: FAILED (absmax 0.039). z from dequantized x planes added
//   ~3e-5 noise on z; top-k tie-flips amplified it. RULE: z needs exact x.
// R14 POST-MORTEM: replay epilogue reading outF through its own non-const
//   pointer -> compiler-assumed aliasing serialized the epilogue (45->66us).
// R15: Zprev via separate const __restrict__ -> 48us, bit-exact. Net ~ R11.
// R16: 8-wave (512-thread) big-GEMM block. The 4-wave block's acc[4][4]x2
//   = 128 acc regs/lane + ~112 VGPR -> ~240 combined -> 2 waves/SIMD
//   reg-capped (and 64KB LDS -> 2 blocks/CU): occupancy wall at 8 waves/CU.
//   Same 128x128 tile split over 8 waves: wave tile 32x64, acc 64 regs,
//   total ~127 -> fits 4 waves/SIMD (__launch_bounds__(512,4)); 2 blocks x
//   8 waves = 16 waves/CU (2x TLP). Same staging traffic, same schedule
//   (loads/thread/tile 8->4 -> vmcnt(4)). Bit-identical math. r-GEMM keeps
//   its proven 256-thread shape via the generalized template.
// shrink = exact k-th-largest |z| via binary search on float bits.
// ---------------------------------------------------------------------------

typedef int int4v __attribute__((ext_vector_type(4)));

__device__ __forceinline__ void quant2(float v, float inv_s,
                                       signed char& q1, signed char& q0) {
    int q = __float2int_rn(v * inv_s);
    q = q > 16256 ? 16256 : (q < -16256 ? -16256 : q);
    int hi = (q + 64) >> 7;            // round-half-up -> [-127,127]
    q1 = (signed char)hi;
    q0 = (signed char)(q - (hi << 7)); // [-64,63]
}

__device__ __forceinline__ void gl_lds16(const signed char* g, signed char* lds) {
    __builtin_amdgcn_global_load_lds(
        (const __attribute__((address_space(1))) void*)g,
        (__attribute__((address_space(3))) void*)lds, 16, 0, 0);
}

// out[m][n] = epilogue( sum_k Aop[m][k]*Bop[k][n] ); Bop in B^T layout [n][k].
// Block tile 128 x BN; WM x WN waves of 64 lanes (NTHR = WM*WN*64).
// Wave tile = (128/WM) x (BN/WN); MI/NJf = frags per wave in m/n.
// EPI 0: outF = mu * v                   (x0; A=y planes, B=AT planes)
// EPI 1: outF = v - Yaux                 (r;  A=x planes, B=A planes)
// EPI 2: outF = replay(Zprev) - mu * v   (z;  A=r planes, B=AT planes;
//         replay(z) = |z|>=thr ? z : copysign(max(|z|-betaPrev,0), z))
template<int BN, int WM, int WN, int EPI>
__global__ __launch_bounds__(WM * WN * 64, (WM * WN == 8) ? 4 : 2)
void gemm_i8(
    const signed char* __restrict__ A1, const signed char* __restrict__ A0, int lda,
    const signed char* __restrict__ B1, const signed char* __restrict__ B0, int ldb,
    const float* __restrict__ sAv,   // per-row scale of A-operand
    const float* __restrict__ sBv,   // per-row scale of B-operand (per out col)
    const float* __restrict__ Yaux,  // EPI1: y fp32
    const float* __restrict__ Zprev, // EPI2: z_{t-1} fp32 (= outF buffer)
    const float* __restrict__ thrv,  // EPI2: per-row shrink threshold (t-1)
    const float* __restrict__ bPrev, // EPI2: &beta[t-1]
    float* __restrict__ outF,
    const float* __restrict__ muPtr, int muIdx, int K, int ldOut)
{
    constexpr int NTHR = WM * WN * 64;
    constexpr int MI   = 128 / WM / 16;   // m-frags per wave
    constexpr int NJf  = BN / WN / 16;    // n-frags per wave
    constexpr int AR   = 512 / NTHR;      // A 16B-chunk iters per plane
    constexpr int BR   = (BN * 4) / NTHR; // B 16B-chunk iters per plane
    constexpr int LPT  = 2 * (AR + BR);   // gl_lds loads per tile per thread

    __shared__ signed char As1[2][128 * 64];
    __shared__ signed char As0[2][128 * 64];
    __shared__ signed char Bs1[2][BN * 64];
    __shared__ signed char Bs0[2][BN * 64];

    const int tid  = threadIdx.x;
    const int wid  = tid >> 6;
    const int lane = tid & 63;
    const int quad = lane >> 4;
    const int l16  = lane & 15;
    const int waveM = (wid / WN) * (MI * 16);
    const int waveN = (wid % WN) * (NJf * 16);
    const int swz   = (l16 >> 1) & 3;          // read-side XOR (rows: base%16==0)

    const int flat  = blockIdx.x + gridDim.x * blockIdx.y;
    const int mBase = (flat & 63) * 128;
    const int nBase = (flat >> 6) * BN;

    int4v accH[MI][NJf] = {};
    int4v accM[MI][NJf] = {};

    // Stage one 64-K tile into buffer b. LDS dest linear (global_load_lds
    // requirement); the global SOURCE chunk is XOR-swizzled so that the
    // ds_read below, applying the same XOR, sees logical chunk order.
    auto stage = [&](int b, int k0) {
        #pragma unroll
        for (int rr = 0; rr < AR; ++rr) {
            int c   = rr * NTHR + tid;         // 16B chunk id
            int row = c >> 2;
            int js  = (c & 3) ^ ((row >> 1) & 3);
            size_t ga = (size_t)(mBase + row) * lda + k0 + js * 16;
            size_t doff = (size_t)((rr * NTHR + wid * 64) * 16);
            gl_lds16(A1 + ga, As1[b] + doff);
            gl_lds16(A0 + ga, As0[b] + doff);
        }
        #pragma unroll
        for (int rr = 0; rr < BR; ++rr) {
            int c   = rr * NTHR + tid;
            int row = c >> 2;
            int js  = (c & 3) ^ ((row >> 1) & 3);
            size_t gb = (size_t)(nBase + row) * ldb + k0 + js * 16;
            size_t doff = (size_t)((rr * NTHR + wid * 64) * 16);
            gl_lds16(B1 + gb, Bs1[b] + doff);
            gl_lds16(B0 + gb, Bs0[b] + doff);
        }
    };

    const int KT = K >> 6;
    stage(0, 0);

    for (int kt = 0; kt < KT; ++kt) {
        const int cur = kt & 1;
        if (kt + 1 < KT) {
            stage(cur ^ 1, (kt + 1) << 6);
            // wait tile-kt's loads only; tile-(kt+1)'s LPT stay in flight
            if constexpr (LPT == 4)      asm volatile("s_waitcnt vmcnt(4)" ::: "memory");
            else if constexpr (LPT == 6) asm volatile("s_waitcnt vmcnt(6)" ::: "memory");
            else                         asm volatile("s_waitcnt vmcnt(8)" ::: "memory");
        } else {
            asm volatile("s_waitcnt vmcnt(0)" ::: "memory");
        }
        __builtin_amdgcn_s_barrier();          // raw: no vmcnt drain

        int4v a1[MI], a0[MI], b1[NJf], b0[NJf];
        #pragma unroll
        for (int i = 0; i < MI; ++i) {
            int off = (waveM + i * 16 + l16) * 64 + ((quad ^ swz) * 16);
            a1[i] = *(const int4v*)(&As1[cur][off]);
            a0[i] = *(const int4v*)(&As0[cur][off]);
        }
        #pragma unroll
        for (int j = 0; j < NJf; ++j) {
            int off = (waveN + j * 16 + l16) * 64 + ((quad ^ swz) * 16);
            b1[j] = *(const int4v*)(&Bs1[cur][off]);
            b0[j] = *(const int4v*)(&Bs0[cur][off]);
        }
        __builtin_amdgcn_s_setprio(1);
        #pragma unroll
        for (int i = 0; i < MI; ++i)
            #pragma unroll
            for (int j = 0; j < NJf; ++j) {
                accH[i][j] = __builtin_amdgcn_mfma_i32_16x16x64_i8(a1[i], b1[j], accH[i][j], 0, 0, 0);
                accM[i][j] = __builtin_amdgcn_mfma_i32_16x16x64_i8(a1[i], b0[j], accM[i][j], 0, 0, 0);
                accM[i][j] = __builtin_amdgcn_mfma_i32_16x16x64_i8(a0[i], b1[j], accM[i][j], 0, 0, 0);
            }
        __builtin_amdgcn_s_setprio(0);
        __builtin_amdgcn_s_barrier();          // reads of buf[cur] done before
                                               // next iter's stage overwrites it
    }

    const float mu = muPtr[muIdx];
    const float betaPrev = (EPI == 2) ? bPrev[0] : 0.f;
    #pragma unroll
    for (int i = 0; i < MI; ++i) {
        #pragma unroll
        for (int j = 0; j < NJf; ++j) {
            const int gr0 = mBase + waveM + i * 16 + quad * 4;
            const int gc  = nBase + waveN + j * 16 + l16;
            const float sB = sBv[gc];
            #pragma unroll
            for (int r2 = 0; r2 < 4; ++r2) {
                const int    gr  = gr0 + r2;
                const size_t idx = (size_t)gr * ldOut + gc;
                const float  sA  = sAv[gr];
                float v = sA * sB * ((float)accH[i][j][r2] * 16384.f
                                   + (float)accM[i][j][r2] * 128.f);
                if constexpr (EPI == 0) {
                    outF[idx] = mu * v;
                } else if constexpr (EPI == 1) {
                    outF[idx] = v - Yaux[idx];
                } else {
                    // bit-exact shrink replay of z_{t-1} (same ops as
                    // shrink_kernel: uint-bit compare, fmaxf, copysignf)
                    const float    zp = Zprev[idx];
                    const unsigned ab = __float_as_uint(fabsf(zp));
                    float xv;
                    if (ab >= __float_as_uint(thrv[gr])) {
                        xv = zp;
                    } else {
                        xv = copysignf(
                            fmaxf(__uint_as_float(ab) - betaPrev, 0.f), zp);
                    }
                    outF[idx] = xv - mu * v;
                }
            }
        }
    }
}

// per-row quantization of a fp32 matrix to i8 dual planes + row scale
template<int COLS>
__global__ __launch_bounds__(256) void rowquant_kernel(
    const float* __restrict__ src,
    signed char* __restrict__ q1, signed char* __restrict__ q0,
    float* __restrict__ scale)
{
    const int wid  = threadIdx.x >> 6;
    const int lane = threadIdx.x & 63;
    const long long row = (long long)blockIdx.x * 4 + wid;
    constexpr int EP = COLS / 256;   // float4 per lane
    const float* s = src + row * COLS;

    float v[EP * 4];
    #pragma unroll
    for (int c = 0; c < EP; ++c) {
        float4 f = ((const float4*)s)[c * 64 + lane];
        v[c * 4 + 0] = f.x; v[c * 4 + 1] = f.y; v[c * 4 + 2] = f.z; v[c * 4 + 3] = f.w;
    }
    float mx = 0.f;
    #pragma unroll
    for (int i = 0; i < EP * 4; ++i) mx = fmaxf(mx, fabsf(v[i]));
    #pragma unroll
    for (int off = 32; off >= 1; off >>= 1) mx = fmaxf(mx, __shfl_xor(mx, off, 64));
    mx = fmaxf(mx, 1e-20f);
    if (lane == 0) scale[row] = mx / 16256.f;
    const float inv = 16256.f / mx;

    #pragma unroll
    for (int c = 0; c < EP; ++c) {
        size_t col = (size_t)(c * 64 + lane) * 4;
        signed char h[4], l[4];
        #pragma unroll
        for (int e = 0; e < 4; ++e) quant2(v[c * 4 + e], inv, h[e], l[e]);
        *(char4*)(q1 + row * COLS + col) = *(char4*)h;
        *(char4*)(q0 + row * COLS + col) = *(char4*)l;
    }
}

// R11/R14: one wave per row of z[.,2048]: exact k-th-largest |z| hard/soft
// threshold via scalar binary search on float bits with ballot counting +
// uniform early exit. Publishes per-row thr (for the next z-GEMM's exact
// replay), quantizes x -> i8 planes + scale (writePlanes), optionally
// writes x fp32 (writeF32, final iteration only).
__global__ __launch_bounds__(256) void shrink_kernel(
    float* __restrict__ z,
    signed char* __restrict__ X1, signed char* __restrict__ X0,
    float* __restrict__ sX, float* __restrict__ thrOut,
    const float* __restrict__ betaPtr, int tIdx, int kSel,
    int writeF32, int writePlanes)
{
    const int wid  = threadIdx.x >> 6;
    const int lane = threadIdx.x & 63;
    const long long row = (long long)blockIdx.x * 4 + wid;
    float* zr = z + row * 2048;

    float v[32];
    #pragma unroll
    for (int c = 0; c < 8; ++c) {
        float4 f = ((const float4*)zr)[c * 64 + lane];
        v[c * 4 + 0] = f.x; v[c * 4 + 1] = f.y; v[c * 4 + 2] = f.z; v[c * 4 + 3] = f.w;
    }

    if (kSel > 0) {
        const float beta = betaPtr[tIdx];
        unsigned a[32];
        #pragma unroll
        for (int i = 0; i < 32; ++i) a[i] = __float_as_uint(fabsf(v[i]));

        // invariant: cnt(>=lo) >= k, cnt(>=hi) < k. Early exit: any mid
        // with cnt(>=mid)==k classifies exactly the top-k set (identical
        // to thr = k-th largest); a tie straddling k makes cnt==k
        // unreachable -> loop runs to convergence (thr = v_k), also exact.
        unsigned lo = 0u, hi = 0x7F800000u;
        #pragma unroll 1
        for (int it = 0; it < 31; ++it) {
            const unsigned mid = (lo + hi) >> 1;
            int cnt = 0;
            #pragma unroll
            for (int i = 0; i < 32; ++i)
                cnt += (int)__popcll(__ballot(a[i] >= mid));
            if (cnt >= kSel) {
                lo = mid;
                if (cnt == kSel) break;
            } else {
                hi = mid;
            }
        }
        const unsigned thr = lo;
        if (lane == 0) thrOut[row] = __uint_as_float(thr);
        #pragma unroll
        for (int i = 0; i < 32; ++i) {
            if (a[i] < thr) {
                float av   = __uint_as_float(a[i]);
                float soft = fmaxf(av - beta, 0.f);
                v[i] = copysignf(soft, v[i]);
            }
        }
    } else {
        // no thresholding this step: replay must be identity -> thr = 0
        if (lane == 0) thrOut[row] = 0.f;
    }

    float mx = 0.f;
    #pragma unroll
    for (int i = 0; i < 32; ++i) mx = fmaxf(mx, fabsf(v[i]));
    #pragma unroll
    for (int off = 32; off >= 1; off >>= 1) mx = fmaxf(mx, __shfl_xor(mx, off, 64));
    mx = fmaxf(mx, 1e-20f);
    if (writePlanes && lane == 0) sX[row] = mx / 16256.f;
    const float inv = 16256.f / mx;

    #pragma unroll
    for (int c = 0; c < 8; ++c) {
        size_t col = (size_t)(c * 64 + lane) * 4;
        if (writePlanes) {
            signed char h[4], l[4];
            #pragma unroll
            for (int e = 0; e < 4; ++e) quant2(v[c * 4 + e], inv, h[e], l[e]);
            *(char4*)(X1 + row * 2048 + col) = *(char4*)h;
            *(char4*)(X0 + row * 2048 + col) = *(char4*)l;
        }
        if (writeF32) {
            float4 f;
            f.x = v[c * 4 + 0]; f.y = v[c * 4 + 1]; f.z = v[c * 4 + 2]; f.w = v[c * 4 + 3];
            ((float4*)zr)[c * 64 + lane] = f;
        }
    }
}

extern "C" void kernel_launch(void* const* d_in, const int* in_sizes, int n_in,
                              void* d_out, int out_size, void* d_ws, size_t ws_size,
                              hipStream_t stream)
{
    const float* y    = (const float*)d_in[0];   // [8192,512]
    const float* A    = (const float*)d_in[1];   // [512,2048]
    const float* W    = (const float*)d_in[2];   // [2048,512] == A^T
    const float* beta = (const float*)d_in[3];   // [6]
    const float* mu   = (const float*)d_in[4];   // [6]
    float* out = (float*)d_out;                  // x / z fp32, in place

    // workspace (~68 MB)
    signed char* A1q  = (signed char*)d_ws;          // [512][2048]
    signed char* A0q  = A1q  + 512 * 2048;
    signed char* AT1q = A0q  + 512 * 2048;           // [2048][512]
    signed char* AT0q = AT1q + 2048 * 512;
    signed char* y1q  = AT0q + 2048 * 512;           // [8192][512]
    signed char* y0q  = y1q  + 8192 * 512;
    signed char* x1q  = y0q  + 8192 * 512;           // [8192][2048]
    signed char* x0q  = x1q  + (size_t)8192 * 2048;
    signed char* r1q  = x0q  + (size_t)8192 * 2048;  // [8192][512]
    signed char* r0q  = r1q  + 8192 * 512;
    float* rF  = (float*)(r0q + 8192 * 512);         // [8192][512] fp32
    float* sa  = rF + (size_t)8192 * 512;            // [512]
    float* sat = sa  + 512;                          // [2048]
    float* sy  = sat + 2048;                         // [8192]
    float* sx  = sy  + 8192;                         // [8192]
    float* sr  = sx  + 8192;                         // [8192]
    float* thr = sr  + 8192;                         // [8192]

    rowquant_kernel<2048><<<128, 256, 0, stream>>>(A, A1q, A0q, sa);
    rowquant_kernel<512><<<512, 256, 0, stream>>>(W, AT1q, AT0q, sat);
    rowquant_kernel<512><<<2048, 256, 0, stream>>>(y, y1q, y0q, sy);

    // x0 = mu0 * y @ A  -> d_out fp32   (A-op = y planes, B-op = AT planes)
    // R16: 8-wave 512-thread blocks, same 128x128 tile.
    gemm_i8<128, 4, 2, 0><<<dim3(16, 64), 512, 0, stream>>>(
        y1q, y0q, 512, AT1q, AT0q, 512, sy, sat,
        nullptr, nullptr, nullptr, nullptr, out, mu, 0, 512, 2048);
    // quantize x0 for GEMM use; thr=0 so the t=1 replay is identity
    shrink_kernel<<<2048, 256, 0, stream>>>(out, x1q, x0q, sx, thr, beta,
                                            0, 0, 0, 1);

    for (int t = 1; t <= 5; ++t) {
        double p = 0.012 * t; if (p > 0.12) p = 0.12;
        int kSel = (int)(p * 2048.0);   // 24,49,73,98,122

        // r = x @ A^T - y  -> rF fp32   (A-op = x planes, B-op = A planes)
        gemm_i8<64, 2, 2, 1><<<dim3(8, 64), 256, 0, stream>>>(
            x1q, x0q, 2048, A1q, A0q, 2048, sx, sa,
            y, nullptr, nullptr, nullptr, rF, mu, t, 2048, 512);
        // quantize r per-row
        rowquant_kernel<512><<<2048, 256, 0, stream>>>(rF, r1q, r0q, sr);

        // z = replay(z_{t-1}) - mu_t * (r @ A)  in place over d_out
        // (Zprev = out read via const __restrict__, R15's measured-fast form)
        gemm_i8<128, 4, 2, 2><<<dim3(16, 64), 512, 0, stream>>>(
            r1q, r0q, 512, AT1q, AT0q, 512, sr, sat,
            nullptr, out, thr, beta + (t - 1), out, mu, t, 512, 2048);

        // x = shrink(z): t<5 -> planes+thr only; t=5 -> fp32 output only
        shrink_kernel<<<2048, 256, 0, stream>>>(out, x1q, x0q, sx, thr, beta,
                                                t, kSel, t == 5 ? 1 : 0,
                                                t < 5 ? 1 : 0);
    }
}

// Round 9
// 710.495 us; speedup vs baseline: 1.1610x; 1.0306x over previous
//
#include <hip/hip_runtime.h>

// ---------------------------------------------------------------------------
// TiLISTA: M=512, N=2048, B=8192, T=5 — i8 dual-plane GEMMs, fp32 z/x state.
//   x0 = mu0 * y @ A                      (fp32 in d_out)
//   for t=1..5:
//     r = x @ A^T - y        (fp32 in ws -> per-row i8 planes)
//     z = x - mu_t * (r @ A) (x REPLAYED bit-exactly from z_{t-1}+thr+beta
//                             inside the epilogue; z written in place)
//     x = shrink(z,beta,k)   (planes for next GEMM + thr row; fp32 only t=5)
// GEMM operands: per-row q = q1*128 + q0 (|q|<=16256, ~15 bits of rowmax).
// 3 x mfma_i32_16x16x64_i8 per 64-K: a1b1->accH, a1b0+a0b1->accM;
// v = sA*sB*(accH*16384 + accM*128).
// Grid flat-swizzle: m-block = flat%64 -> same-m blocks share an XCD L2 (R6).
// R9: GEMM schedule rewrite (T2+T3+T4+T5): LDS double-buffer + prefetch-
//   before-compute, raw s_barrier + counted s_waitcnt vmcnt(L), XOR-swizzled
//   tiles (source-side pre-swizzle, read-side XOR), s_setprio around MFMA.
// R10 POST-MORTEM: 2-rows/wave shrink REGRESSED (occupancy halved). Reverted.
// R11: shrink: ballot counting + uniform early exit (exact same top-k set).
// R12 POST-MORTEM: NJ=2 big GEMM REGRESSED (staging overhead/FLOP doubled).
// R13 POST-MORTEM: FAILED. z from dequantized x planes -> tie-flip blowup.
//   RULE: z needs bit-exact x.
// R14 POST-MORTEM: replay epilogue reading outF through its own pointer ->
//   compiler-assumed aliasing serialized the epilogue (45->66us).
// R15: Zprev via separate const __restrict__ -> bit-exact, 48us.
// R16: 8-wave 512-thread big-GEMM block: acc/lane 128->64 regs, occupancy
//   18.5->32%. dur only 48->45: occupancy was secondary.
// R17: LDS-transposed epilogue. 120 of the 128 MB/dispatch is epilogue
//   traffic (Zprev+z), issued as scattered 4B accesses (fragment layout =
//   4 same-col rows per lane) -> 2.9 TB/s achieved. Fix: after the K-loop
//   the staging LDS is dead and exactly fits the fp32 tile; ds_write acc
//   in fragment layout, barrier, then 8 coalesced passes of float4 loads
//   (Zprev/Yaux) + float4 stores. Same per-element fp32 ops -> bit-exact.
// shrink = exact k-th-largest |z| via binary search on float bits.
// ---------------------------------------------------------------------------

typedef int int4v __attribute__((ext_vector_type(4)));

__device__ __forceinline__ void quant2(float v, float inv_s,
                                       signed char& q1, signed char& q0) {
    int q = __float2int_rn(v * inv_s);
    q = q > 16256 ? 16256 : (q < -16256 ? -16256 : q);
    int hi = (q + 64) >> 7;            // round-half-up -> [-127,127]
    q1 = (signed char)hi;
    q0 = (signed char)(q - (hi << 7)); // [-64,63]
}

__device__ __forceinline__ void gl_lds16(const signed char* g, signed char* lds) {
    __builtin_amdgcn_global_load_lds(
        (const __attribute__((address_space(1))) void*)g,
        (__attribute__((address_space(3))) void*)lds, 16, 0, 0);
}

// out[m][n] = epilogue( sum_k Aop[m][k]*Bop[k][n] ); Bop in B^T layout [n][k].
// Block tile 128 x BN; WM x WN waves of 64 lanes (NTHR = WM*WN*64).
// EPI 0: outF = mu * v                   (x0; A=y planes, B=AT planes)
// EPI 1: outF = v - Yaux                 (r;  A=x planes, B=A planes)
// EPI 2: outF = replay(Zprev) - mu * v   (z;  A=r planes, B=AT planes;
//         replay(z) = |z|>=thr ? z : copysign(max(|z|-betaPrev,0), z))
template<int BN, int WM, int WN, int EPI>
__global__ __launch_bounds__(WM * WN * 64, (WM * WN == 8) ? 4 : 2)
void gemm_i8(
    const signed char* __restrict__ A1, const signed char* __restrict__ A0, int lda,
    const signed char* __restrict__ B1, const signed char* __restrict__ B0, int ldb,
    const float* __restrict__ sAv,   // per-row scale of A-operand
    const float* __restrict__ sBv,   // per-row scale of B-operand (per out col)
    const float* __restrict__ Yaux,  // EPI1: y fp32
    const float* __restrict__ Zprev, // EPI2: z_{t-1} fp32 (= outF buffer)
    const float* __restrict__ thrv,  // EPI2: per-row shrink threshold (t-1)
    const float* __restrict__ bPrev, // EPI2: &beta[t-1]
    float* __restrict__ outF,
    const float* __restrict__ muPtr, int muIdx, int K, int ldOut)
{
    constexpr int NTHR = WM * WN * 64;
    constexpr int MI   = 128 / WM / 16;   // m-frags per wave
    constexpr int NJf  = BN / WN / 16;    // n-frags per wave
    constexpr int AR   = 512 / NTHR;      // A 16B-chunk iters per plane
    constexpr int BR   = (BN * 4) / NTHR; // B 16B-chunk iters per plane
    constexpr int LPT  = 2 * (AR + BR);   // gl_lds loads per tile per thread
    constexpr int ASZ  = 128 * 64;        // one A staging buffer (bytes)
    constexpr int BSZ  = BN * 64;         // one B staging buffer (bytes)

    // staging buffers; after the K-loop, reused as fp32 epi tile [128][BN]
    // (epi tile = 128*BN*4 bytes <= 4*ASZ + 4*BSZ for BN in {64,128})
    __shared__ signed char smem[4 * ASZ + 4 * BSZ];
    signed char* const As1p = smem;                       // [2][ASZ]
    signed char* const As0p = smem + 2 * ASZ;             // [2][ASZ]
    signed char* const Bs1p = smem + 4 * ASZ;             // [2][BSZ]
    signed char* const Bs0p = smem + 4 * ASZ + 2 * BSZ;   // [2][BSZ]

    const int tid  = threadIdx.x;
    const int wid  = tid >> 6;
    const int lane = tid & 63;
    const int quad = lane >> 4;
    const int l16  = lane & 15;
    const int waveM = (wid / WN) * (MI * 16);
    const int waveN = (wid % WN) * (NJf * 16);
    const int swz   = (l16 >> 1) & 3;          // read-side XOR (rows: base%16==0)

    const int flat  = blockIdx.x + gridDim.x * blockIdx.y;
    const int mBase = (flat & 63) * 128;
    const int nBase = (flat >> 6) * BN;

    int4v accH[MI][NJf] = {};
    int4v accM[MI][NJf] = {};

    // Stage one 64-K tile into buffer b. LDS dest linear (global_load_lds
    // requirement); the global SOURCE chunk is XOR-swizzled so that the
    // ds_read below, applying the same XOR, sees logical chunk order.
    auto stage = [&](int b, int k0) {
        #pragma unroll
        for (int rr = 0; rr < AR; ++rr) {
            int c   = rr * NTHR + tid;         // 16B chunk id
            int row = c >> 2;
            int js  = (c & 3) ^ ((row >> 1) & 3);
            size_t ga = (size_t)(mBase + row) * lda + k0 + js * 16;
            size_t doff = (size_t)(b * ASZ + (rr * NTHR + wid * 64) * 16);
            gl_lds16(A1 + ga, As1p + doff);
            gl_lds16(A0 + ga, As0p + doff);
        }
        #pragma unroll
        for (int rr = 0; rr < BR; ++rr) {
            int c   = rr * NTHR + tid;
            int row = c >> 2;
            int js  = (c & 3) ^ ((row >> 1) & 3);
            size_t gb = (size_t)(nBase + row) * ldb + k0 + js * 16;
            size_t doff = (size_t)(b * BSZ + (rr * NTHR + wid * 64) * 16);
            gl_lds16(B1 + gb, Bs1p + doff);
            gl_lds16(B0 + gb, Bs0p + doff);
        }
    };

    const int KT = K >> 6;
    stage(0, 0);

    for (int kt = 0; kt < KT; ++kt) {
        const int cur = kt & 1;
        if (kt + 1 < KT) {
            stage(cur ^ 1, (kt + 1) << 6);
            // wait tile-kt's loads only; tile-(kt+1)'s LPT stay in flight
            if constexpr (LPT == 4)      asm volatile("s_waitcnt vmcnt(4)" ::: "memory");
            else if constexpr (LPT == 6) asm volatile("s_waitcnt vmcnt(6)" ::: "memory");
            else                         asm volatile("s_waitcnt vmcnt(8)" ::: "memory");
        } else {
            asm volatile("s_waitcnt vmcnt(0)" ::: "memory");
        }
        __builtin_amdgcn_s_barrier();          // raw: no vmcnt drain

        int4v a1[MI], a0[MI], b1[NJf], b0[NJf];
        #pragma unroll
        for (int i = 0; i < MI; ++i) {
            int off = (waveM + i * 16 + l16) * 64 + ((quad ^ swz) * 16);
            a1[i] = *(const int4v*)(As1p + cur * ASZ + off);
            a0[i] = *(const int4v*)(As0p + cur * ASZ + off);
        }
        #pragma unroll
        for (int j = 0; j < NJf; ++j) {
            int off = (waveN + j * 16 + l16) * 64 + ((quad ^ swz) * 16);
            b1[j] = *(const int4v*)(Bs1p + cur * BSZ + off);
            b0[j] = *(const int4v*)(Bs0p + cur * BSZ + off);
        }
        __builtin_amdgcn_s_setprio(1);
        #pragma unroll
        for (int i = 0; i < MI; ++i)
            #pragma unroll
            for (int j = 0; j < NJf; ++j) {
                accH[i][j] = __builtin_amdgcn_mfma_i32_16x16x64_i8(a1[i], b1[j], accH[i][j], 0, 0, 0);
                accM[i][j] = __builtin_amdgcn_mfma_i32_16x16x64_i8(a1[i], b0[j], accM[i][j], 0, 0, 0);
                accM[i][j] = __builtin_amdgcn_mfma_i32_16x16x64_i8(a0[i], b1[j], accM[i][j], 0, 0, 0);
            }
        __builtin_amdgcn_s_setprio(0);
        __builtin_amdgcn_s_barrier();          // reads of buf[cur] done before
                                               // next iter's stage overwrites it
    }

    // ---- epilogue: acc -> LDS tile (fragment layout), then coalesced
    //      float4 global I/O (R17). Same per-element fp32 ops -> bit-exact.
    const float mu = muPtr[muIdx];
    const float betaPrev = (EPI == 2) ? bPrev[0] : 0.f;
    float* const epi = (float*)smem;           // [128][BN]

    #pragma unroll
    for (int i = 0; i < MI; ++i) {
        #pragma unroll
        for (int j = 0; j < NJf; ++j) {
            const int lr0 = waveM + i * 16 + quad * 4;
            const int lc  = waveN + j * 16 + l16;
            const float sB = sBv[nBase + lc];
            #pragma unroll
            for (int r2 = 0; r2 < 4; ++r2) {
                const int lr = lr0 + r2;
                const float sA = sAv[mBase + lr];
                epi[lr * BN + lc] = sA * sB *
                    ((float)accH[i][j][r2] * 16384.f
                   + (float)accM[i][j][r2] * 128.f);
            }
        }
    }
    __syncthreads();

    constexpr int C4   = BN / 4;               // float4 per tile row
    constexpr int PASS = (128 * C4) / NTHR;    // = 8 for both shapes
    #pragma unroll
    for (int p = 0; p < PASS; ++p) {
        const int e  = p * NTHR + tid;
        const int lr = e / C4;
        const int c4 = e % C4;
        const int gr = mBase + lr;
        const size_t idx = (size_t)gr * ldOut + nBase + c4 * 4;
        const float4 v4 = *(const float4*)&epi[lr * BN + c4 * 4];
        float4 o;
        if constexpr (EPI == 0) {
            o.x = mu * v4.x; o.y = mu * v4.y;
            o.z = mu * v4.z; o.w = mu * v4.w;
        } else if constexpr (EPI == 1) {
            const float4 ya = *(const float4*)&Yaux[idx];
            o.x = v4.x - ya.x; o.y = v4.y - ya.y;
            o.z = v4.z - ya.z; o.w = v4.w - ya.w;
        } else {
            const float4 zp = *(const float4*)&Zprev[idx];
            const unsigned tb = __float_as_uint(thrv[gr]);
            const float zc[4] = {zp.x, zp.y, zp.z, zp.w};
            const float vc[4] = {v4.x, v4.y, v4.z, v4.w};
            float oc[4];
            #pragma unroll
            for (int k4 = 0; k4 < 4; ++k4) {
                // bit-exact shrink replay of z_{t-1} (same ops as
                // shrink_kernel: uint-bit compare, fmaxf, copysignf)
                const unsigned ab = __float_as_uint(fabsf(zc[k4]));
                float xv;
                if (ab >= tb) {
                    xv = zc[k4];
                } else {
                    xv = copysignf(
                        fmaxf(__uint_as_float(ab) - betaPrev, 0.f), zc[k4]);
                }
                oc[k4] = xv - mu * vc[k4];
            }
            o.x = oc[0]; o.y = oc[1]; o.z = oc[2]; o.w = oc[3];
        }
        *(float4*)&outF[idx] = o;
    }
}

// per-row quantization of a fp32 matrix to i8 dual planes + row scale
template<int COLS>
__global__ __launch_bounds__(256) void rowquant_kernel(
    const float* __restrict__ src,
    signed char* __restrict__ q1, signed char* __restrict__ q0,
    float* __restrict__ scale)
{
    const int wid  = threadIdx.x >> 6;
    const int lane = threadIdx.x & 63;
    const long long row = (long long)blockIdx.x * 4 + wid;
    constexpr int EP = COLS / 256;   // float4 per lane
    const float* s = src + row * COLS;

    float v[EP * 4];
    #pragma unroll
    for (int c = 0; c < EP; ++c) {
        float4 f = ((const float4*)s)[c * 64 + lane];
        v[c * 4 + 0] = f.x; v[c * 4 + 1] = f.y; v[c * 4 + 2] = f.z; v[c * 4 + 3] = f.w;
    }
    float mx = 0.f;
    #pragma unroll
    for (int i = 0; i < EP * 4; ++i) mx = fmaxf(mx, fabsf(v[i]));
    #pragma unroll
    for (int off = 32; off >= 1; off >>= 1) mx = fmaxf(mx, __shfl_xor(mx, off, 64));
    mx = fmaxf(mx, 1e-20f);
    if (lane == 0) scale[row] = mx / 16256.f;
    const float inv = 16256.f / mx;

    #pragma unroll
    for (int c = 0; c < EP; ++c) {
        size_t col = (size_t)(c * 64 + lane) * 4;
        signed char h[4], l[4];
        #pragma unroll
        for (int e = 0; e < 4; ++e) quant2(v[c * 4 + e], inv, h[e], l[e]);
        *(char4*)(q1 + row * COLS + col) = *(char4*)h;
        *(char4*)(q0 + row * COLS + col) = *(char4*)l;
    }
}

// R11/R14: one wave per row of z[.,2048]: exact k-th-largest |z| hard/soft
// threshold via scalar binary search on float bits with ballot counting +
// uniform early exit. Publishes per-row thr (for the next z-GEMM's exact
// replay), quantizes x -> i8 planes + scale (writePlanes), optionally
// writes x fp32 (writeF32, final iteration only).
__global__ __launch_bounds__(256) void shrink_kernel(
    float* __restrict__ z,
    signed char* __restrict__ X1, signed char* __restrict__ X0,
    float* __restrict__ sX, float* __restrict__ thrOut,
    const float* __restrict__ betaPtr, int tIdx, int kSel,
    int writeF32, int writePlanes)
{
    const int wid  = threadIdx.x >> 6;
    const int lane = threadIdx.x & 63;
    const long long row = (long long)blockIdx.x * 4 + wid;
    float* zr = z + row * 2048;

    float v[32];
    #pragma unroll
    for (int c = 0; c < 8; ++c) {
        float4 f = ((const float4*)zr)[c * 64 + lane];
        v[c * 4 + 0] = f.x; v[c * 4 + 1] = f.y; v[c * 4 + 2] = f.z; v[c * 4 + 3] = f.w;
    }

    if (kSel > 0) {
        const float beta = betaPtr[tIdx];
        unsigned a[32];
        #pragma unroll
        for (int i = 0; i < 32; ++i) a[i] = __float_as_uint(fabsf(v[i]));

        // invariant: cnt(>=lo) >= k, cnt(>=hi) < k. Early exit: any mid
        // with cnt(>=mid)==k classifies exactly the top-k set (identical
        // to thr = k-th largest); a tie straddling k makes cnt==k
        // unreachable -> loop runs to convergence (thr = v_k), also exact.
        unsigned lo = 0u, hi = 0x7F800000u;
        #pragma unroll 1
        for (int it = 0; it < 31; ++it) {
            const unsigned mid = (lo + hi) >> 1;
            int cnt = 0;
            #pragma unroll
            for (int i = 0; i < 32; ++i)
                cnt += (int)__popcll(__ballot(a[i] >= mid));
            if (cnt >= kSel) {
                lo = mid;
                if (cnt == kSel) break;
            } else {
                hi = mid;
            }
        }
        const unsigned thr = lo;
        if (lane == 0) thrOut[row] = __uint_as_float(thr);
        #pragma unroll
        for (int i = 0; i < 32; ++i) {
            if (a[i] < thr) {
                float av   = __uint_as_float(a[i]);
                float soft = fmaxf(av - beta, 0.f);
                v[i] = copysignf(soft, v[i]);
            }
        }
    } else {
        // no thresholding this step: replay must be identity -> thr = 0
        if (lane == 0) thrOut[row] = 0.f;
    }

    float mx = 0.f;
    #pragma unroll
    for (int i = 0; i < 32; ++i) mx = fmaxf(mx, fabsf(v[i]));
    #pragma unroll
    for (int off = 32; off >= 1; off >>= 1) mx = fmaxf(mx, __shfl_xor(mx, off, 64));
    mx = fmaxf(mx, 1e-20f);
    if (writePlanes && lane == 0) sX[row] = mx / 16256.f;
    const float inv = 16256.f / mx;

    #pragma unroll
    for (int c = 0; c < 8; ++c) {
        size_t col = (size_t)(c * 64 + lane) * 4;
        if (writePlanes) {
            signed char h[4], l[4];
            #pragma unroll
            for (int e = 0; e < 4; ++e) quant2(v[c * 4 + e], inv, h[e], l[e]);
            *(char4*)(X1 + row * 2048 + col) = *(char4*)h;
            *(char4*)(X0 + row * 2048 + col) = *(char4*)l;
        }
        if (writeF32) {
            float4 f;
            f.x = v[c * 4 + 0]; f.y = v[c * 4 + 1]; f.z = v[c * 4 + 2]; f.w = v[c * 4 + 3];
            ((float4*)zr)[c * 64 + lane] = f;
        }
    }
}

extern "C" void kernel_launch(void* const* d_in, const int* in_sizes, int n_in,
                              void* d_out, int out_size, void* d_ws, size_t ws_size,
                              hipStream_t stream)
{
    const float* y    = (const float*)d_in[0];   // [8192,512]
    const float* A    = (const float*)d_in[1];   // [512,2048]
    const float* W    = (const float*)d_in[2];   // [2048,512] == A^T
    const float* beta = (const float*)d_in[3];   // [6]
    const float* mu   = (const float*)d_in[4];   // [6]
    float* out = (float*)d_out;                  // x / z fp32, in place

    // workspace (~68 MB)
    signed char* A1q  = (signed char*)d_ws;          // [512][2048]
    signed char* A0q  = A1q  + 512 * 2048;
    signed char* AT1q = A0q  + 512 * 2048;           // [2048][512]
    signed char* AT0q = AT1q + 2048 * 512;
    signed char* y1q  = AT0q + 2048 * 512;           // [8192][512]
    signed char* y0q  = y1q  + 8192 * 512;
    signed char* x1q  = y0q  + 8192 * 512;           // [8192][2048]
    signed char* x0q  = x1q  + (size_t)8192 * 2048;
    signed char* r1q  = x0q  + (size_t)8192 * 2048;  // [8192][512]
    signed char* r0q  = r1q  + 8192 * 512;
    float* rF  = (float*)(r0q + 8192 * 512);         // [8192][512] fp32
    float* sa  = rF + (size_t)8192 * 512;            // [512]
    float* sat = sa  + 512;                          // [2048]
    float* sy  = sat + 2048;                         // [8192]
    float* sx  = sy  + 8192;                         // [8192]
    float* sr  = sx  + 8192;                         // [8192]
    float* thr = sr  + 8192;                         // [8192]

    rowquant_kernel<2048><<<128, 256, 0, stream>>>(A, A1q, A0q, sa);
    rowquant_kernel<512><<<512, 256, 0, stream>>>(W, AT1q, AT0q, sat);
    rowquant_kernel<512><<<2048, 256, 0, stream>>>(y, y1q, y0q, sy);

    // x0 = mu0 * y @ A  -> d_out fp32   (A-op = y planes, B-op = AT planes)
    gemm_i8<128, 4, 2, 0><<<dim3(16, 64), 512, 0, stream>>>(
        y1q, y0q, 512, AT1q, AT0q, 512, sy, sat,
        nullptr, nullptr, nullptr, nullptr, out, mu, 0, 512, 2048);
    // quantize x0 for GEMM use; thr=0 so the t=1 replay is identity
    shrink_kernel<<<2048, 256, 0, stream>>>(out, x1q, x0q, sx, thr, beta,
                                            0, 0, 0, 1);

    for (int t = 1; t <= 5; ++t) {
        double p = 0.012 * t; if (p > 0.12) p = 0.12;
        int kSel = (int)(p * 2048.0);   // 24,49,73,98,122

        // r = x @ A^T - y  -> rF fp32   (A-op = x planes, B-op = A planes)
        gemm_i8<64, 2, 2, 1><<<dim3(8, 64), 256, 0, stream>>>(
            x1q, x0q, 2048, A1q, A0q, 2048, sx, sa,
            y, nullptr, nullptr, nullptr, rF, mu, t, 2048, 512);
        // quantize r per-row
        rowquant_kernel<512><<<2048, 256, 0, stream>>>(rF, r1q, r0q, sr);

        // z = replay(z_{t-1}) - mu_t * (r @ A)  in place over d_out
        // (Zprev = out read via const __restrict__, R15's measured-fast form)
        gemm_i8<128, 4, 2, 2><<<dim3(16, 64), 512, 0, stream>>>(
            r1q, r0q, 512, AT1q, AT0q, 512, sr, sat,
            nullptr, out, thr, beta + (t - 1), out, mu, t, 512, 2048);

        // x = shrink(z): t<5 -> planes+thr only; t=5 -> fp32 output only
        shrink_kernel<<<2048, 256, 0, stream>>>(out, x1q, x0q, sx, thr, beta,
                                                t, kSel, t == 5 ? 1 : 0,
                                                t < 5 ? 1 : 0);
    }
}